// Round 14
// baseline (91.955 us; speedup 1.0000x reference)
//
#include <hip/hip_runtime.h>

#define C_IN   64
#define HW_DIM 64
#define C_OUT  128
#define NG     8
#define KSPL   4608     // 576 * 8
#define BM     64       // pixels per block = one image row
#define NSPL_STEPS 72   // total spline K-steps of 64
#define NSTEPS 81
#define NHALF  36       // spline steps per K-half
#define NBASE  9
#define NPAD   66
#define NEXP   (8 * C_IN * NPAD * NPAD)   // 2,230,272 padded elements

// d_ws layout (bytes)
#define WT_BYTES 1327104                  // 81*128*64*2
#define XE_OFF   WT_BYTES
#define XE_BYTES (NEXP * NG * 2)          // 35,684,352
#define SE_OFF   (XE_OFF + XE_BYTES)

typedef __attribute__((ext_vector_type(8))) __bf16 bf16x8;
typedef __attribute__((ext_vector_type(4))) float  f32x4;

// --------------------------------------------------------------------------
// Weight prep (r8 layout): wt3[step(81)][wc(4)][n(2)][ks(2)][lane(64)][8],
// co = wc*32 + n*16 + (lane&15), k = step*64 + ks*32 + (lane>>4)*8 + e.
// --------------------------------------------------------------------------
__global__ __launch_bounds__(256)
void prep_wt(const float* __restrict__ sw, const float* __restrict__ bw,
             __bf16* __restrict__ wt3)
{
  const int step = blockIdx.x;
  const int t    = threadIdx.x;
  const int wc   = t >> 6;
  const int lane = t & 63;
  const int l15  = lane & 15;
  const int g4   = lane >> 4;
#pragma unroll
  for (int n = 0; n < 2; ++n)
#pragma unroll
    for (int ks = 0; ks < 2; ++ks) {
      const int co = wc * 32 + n * 16 + l15;
      bf16x8 v;
#pragma unroll
      for (int e = 0; e < 8; ++e) {
        const int k = step * 64 + ks * 32 + g4 * 8 + e;
        float f;
        if (k < KSPL) f = sw[(size_t)k * C_OUT + co];
        else          f = bw[(size_t)(k - KSPL) * C_OUT + co];
        v[e] = (__bf16)f;
      }
      *(bf16x8*)(wt3 + (size_t)step * 8192 + wc * 2048 + (n * 2 + ks) * 512
                 + lane * 8) = v;
    }
}

// --------------------------------------------------------------------------
// Basis/silu expansion: XE[bc][yp][xp][8], SE[bc][yp][xp]; halo = p=0 values.
// --------------------------------------------------------------------------
__global__ __launch_bounds__(256)
void expand(const float* __restrict__ x, const float* __restrict__ grid,
            __bf16* __restrict__ xe, __bf16* __restrict__ se)
{
  const int idx = blockIdx.x * 256 + threadIdx.x;
  if (idx >= NEXP) return;
  const int xp = idx % NPAD;
  const int r  = idx / NPAD;
  const int yp = r % NPAD;
  const int bc = r / NPAD;

  float p = 0.f;
  if (xp >= 1 && xp <= HW_DIM && yp >= 1 && yp <= HW_DIM)
    p = x[(size_t)bc * (HW_DIM * HW_DIM) + (yp - 1) * HW_DIM + (xp - 1)];

  bf16x8 v;
#pragma unroll
  for (int g = 0; g < NG; ++g) {
    const float z = 1.75f * (p - grid[g]);
    v[g] = (__bf16)__expf(-z * z);
  }
  *(bf16x8*)(xe + (size_t)idx * NG) = v;
  const float e = __expf(-p);
  se[idx] = (__bf16)(p * __builtin_amdgcn_rcpf(1.f + e));
}

// --------------------------------------------------------------------------
// Output init: out[b][co][pix] = base_b[co]  (bias; gemm halves atomic-add)
// --------------------------------------------------------------------------
__global__ __launch_bounds__(256)
void init_out(const float* __restrict__ bb, float* __restrict__ out)
{
  const int i4 = blockIdx.x * 256 + threadIdx.x;   // 1,048,576 threads
  const int e  = i4 * 4;
  const float v = bb[(e >> 12) & 127];
  *(f32x4*)(out + e) = f32x4{v, v, v, v};
}

static __device__ __forceinline__ void gload16(const __bf16* g, __bf16* l) {
  __builtin_amdgcn_global_load_lds(
      (const __attribute__((address_space(1))) void*)g,
      (__attribute__((address_space(3))) void*)l, 16, 0, 0);
}

// counted-vmcnt barrier (T4): keep 6 newest VMEM ops in flight across it
#define WAITBAR6() do {                                      \
    asm volatile("s_waitcnt vmcnt(6)" ::: "memory");         \
    __builtin_amdgcn_s_barrier();                            \
    __builtin_amdgcn_sched_barrier(0);                       \
  } while (0)

// --------------------------------------------------------------------------
// GEMM, split-K: 1024 blocks = 512 row-blocks x 2 K-halves; 4 waves of
// 64px x 32co -> 4 blocks/CU, 4 waves/SIMD, per-CU traffic identical to r8.
// Each half: 36 spline steps, r8's distance-2 ring + vmcnt(6) barriers
// (6 VMEM ops/thread/step: 2 gload_lds + 4 b128). Half 1 adds 9 base steps.
// Epilogue: unsafeAtomicAdd into bias-initialized out.
// --------------------------------------------------------------------------
__global__ __launch_bounds__(256, 4)
void kan_gemm(const __bf16* __restrict__ xe, const __bf16* __restrict__ se,
              const __bf16* __restrict__ wt3, float* __restrict__ out)
{
  __shared__ __align__(16) __bf16 As[3][BM][64];   // 3 x 8 KB ring
  __shared__ int tbl[576];                         // c*4356 + kh*66 + kw

  const int t    = threadIdx.x;
  const int lane = t & 63;
  const int wid  = t >> 6;              // 0..3 = co-quarter
  const int l15  = lane & 15;
  const int g4   = lane >> 4;

  // bijective XCD swizzle over 1024 blocks = 8 XCDs x 128
  const int bid = blockIdx.x;
  const int swz = (bid & 7) * 128 + (bid >> 3);
  const int kh  = swz & 1;              // K-half
  const int rb  = swz >> 1;             // row-block 0..511
  const int b   = rb >> 6;              // image
  const int y0  = rb & 63;              // image row
  const int S0  = kh * NHALF;           // first spline step of this half

  for (int f = t; f < 576; f += 256) {
    const int c  = f / 9;
    const int j  = f - 9 * c;
    const int kk = j / 3;
    const int kw = j - 3 * kk;
    tbl[f] = c * 4356 + kk * 66 + kw;
  }

  const int ROW = b * 278784 + y0 * 66;

  // A-staging (r8): slot (px = t>>3 [+32], gslot = t&7) holds feature-granule
  // q = gslot ^ (px&7) of the step (G21 pre-swizzle at the global source).
  const int qsrc  = (lane & 7) ^ ((lane >> 3) & 7);
  const int pbase = (wid << 3) + (lane >> 3);

  f32x4 acc[2][4];
#pragma unroll
  for (int n = 0; n < 2; ++n)
#pragma unroll
    for (int m = 0; m < 4; ++m)
      acc[n][m] = f32x4{0.f, 0.f, 0.f, 0.f};

  auto stageA = [&](int buf, int step) {
    const int off = ROW + tbl[step * 8 + qsrc] + pbase;
    __bf16* dst = &As[buf][0][0] + t * 8;
    gload16(xe + (size_t)off * 8,        dst);
    gload16(xe + (size_t)(off + 32) * 8, dst + 2048);   // pass 1: px += 32
  };

  auto loadB = [&](bf16x8 (&wf)[2][2], int step) {
    const __bf16* wb = wt3 + (size_t)step * 8192 + wid * 2048 + lane * 8;
#pragma unroll
    for (int n = 0; n < 2; ++n)
#pragma unroll
      for (int ks = 0; ks < 2; ++ks)
        wf[n][ks] = *(const bf16x8*)(wb + (n * 2 + ks) * 512);
  };

  auto compute = [&](int buf, bf16x8 (&wf)[2][2]) {
    bf16x8 xf[4][2];
#pragma unroll
    for (int ks = 0; ks < 2; ++ks)
#pragma unroll
      for (int m = 0; m < 4; ++m) {
        const int pr = m * 16 + l15;
        xf[m][ks] = *(const bf16x8*)(&As[buf][pr][(((ks * 4 + g4) ^ (pr & 7)) * 8)]);
      }
#pragma unroll
    for (int ks = 0; ks < 2; ++ks)
#pragma unroll
      for (int n = 0; n < 2; ++n)
#pragma unroll
        for (int m = 0; m < 4; ++m)
          acc[n][m] = __builtin_amdgcn_mfma_f32_16x16x32_bf16(
              wf[n][ks], xf[m][ks], acc[n][m], 0, 0, 0);
  };

  __syncthreads();                      // tbl ready

  // ---- spline half: 36 steps, distance-2 ring, counted-vmcnt barriers ----
  bf16x8 wA[2][2], wB[2][2], wC[2][2];
  stageA(0, S0 + 0); loadB(wA, S0 + 0); // 6 VMEM ops
  stageA(1, S0 + 1); loadB(wB, S0 + 1); // 6 VMEM ops
  WAITBAR6();                           // step-0 landed; step-1 in flight

  for (int s = 0; s < NHALF - 3; s += 3) {
    stageA(2, S0 + s + 2); loadB(wC, S0 + s + 2);
    compute(0, wA);
    WAITBAR6();
    stageA(0, S0 + s + 3); loadB(wA, S0 + s + 3);
    compute(1, wB);
    WAITBAR6();
    stageA(1, S0 + s + 4); loadB(wB, S0 + s + 4);
    compute(2, wC);
    WAITBAR6();
  }
  // steps 33..35 of this half (33/buf0, 34/buf1 staged; stage 35 here)
  stageA(2, S0 + 35); loadB(wC, S0 + 35);
  compute(0, wA);                       // step 33
  WAITBAR6();                           // 34 landed; 35 in flight
  compute(1, wB);                       // step 34
  asm volatile("s_waitcnt vmcnt(0)" ::: "memory");
  __builtin_amdgcn_s_barrier();
  __builtin_amdgcn_sched_barrier(0);
  compute(2, wC);                       // step 35

  // ---- base phase (K-half 1 only): silu(p) patches via LDS, 9 steps ----
  if (kh == 1) {
    const int ROWs = ROW + (t & 63);
    auto stageBase = [&](int buf, int bs) {
      const int px = t & 63;
#pragma unroll
      for (int h = 0; h < 2; ++h) {
        const int q = (t >> 6) + h * 4;   // feature granule 0..7
        bf16x8 v;
#pragma unroll
        for (int jj = 0; jj < 8; ++jj) {
          const int f = bs * 64 + q * 8 + jj;
          v[jj] = se[(size_t)(ROWs + tbl[f])];
        }
        *(bf16x8*)(&As[buf][px][((q ^ (px & 7)) * 8)]) = v;   // lane-varying col
      }
    };
    auto loadBbase = [&](bf16x8 (&wf)[2][2], int bs) {
      loadB(wf, NSPL_STEPS + bs);
    };

    stageBase(0, 0);                    // buf0 free (last compute used buf2)
    __syncthreads();
    for (int bs = 0; bs < NBASE; ++bs) {
      const int cb = bs & 1;
      if (bs + 1 < NBASE) stageBase(cb ^ 1, bs + 1);
      loadBbase(wA, bs);
      compute(cb, wA);
      __syncthreads();
    }
  }

  // ---- epilogue: atomic-add partial D[co][pix] (bias pre-written) ----
#pragma unroll
  for (int n = 0; n < 2; ++n) {
    const int co = wid * 32 + n * 16 + g4 * 4;
#pragma unroll
    for (int m = 0; m < 4; ++m) {
      const int pl = m * 16 + l15;
      float* o = out + (size_t)(b * C_OUT + co) * 4096 + y0 * 64 + pl;
#pragma unroll
      for (int i = 0; i < 4; ++i)
        unsafeAtomicAdd(o + (size_t)i * 4096, acc[n][m][i]);
    }
  }
}

extern "C" void kernel_launch(void* const* d_in, const int* in_sizes, int n_in,
                              void* d_out, int out_size, void* d_ws, size_t ws_size,
                              hipStream_t stream) {
  const float* x    = (const float*)d_in[0];
  const float* grid = (const float*)d_in[1];
  const float* sw   = (const float*)d_in[2];
  const float* bw   = (const float*)d_in[3];
  const float* bb   = (const float*)d_in[4];
  float* out = (float*)d_out;

  __bf16* wt3 = (__bf16*)d_ws;
  __bf16* xe  = (__bf16*)((char*)d_ws + XE_OFF);
  __bf16* se  = (__bf16*)((char*)d_ws + SE_OFF);

  prep_wt<<<NSTEPS, 256, 0, stream>>>(sw, bw, wt3);
  expand<<<(NEXP + 255) / 256, 256, 0, stream>>>(x, grid, xe, se);
  init_out<<<4096, 256, 0, stream>>>(bb, out);
  kan_gemm<<<1024, 256, 0, stream>>>(xe, se, wt3, out);
}

// Round 15
// 82.400 us; speedup vs baseline: 1.1160x; 1.1160x over previous
//
#include <hip/hip_runtime.h>

#define C_IN   64
#define HW_DIM 64
#define C_OUT  128
#define NG     8
#define BM     64       // pixels per block = one image row
#define NSPL_STEPS 72   // spline K-steps of 64 (8 chan-groups x 9 taps)
#define NSTEPS 81
#define NBASE  9
#define NPAD   66

// XE4[b][yp(66)][grp(8)][xp(66)][cg(8)][g(8)] bf16 ; strides (elems):
#define XE_XP   64
#define XE_GRP  4224      // 66*64
#define XE_YP   33792     // 8*4224
#define XE_B    2230272   // 66*33792
// SE4[b][yp(66)][xp(66)][c(64)] bf16
#define SE_XP   64
#define SE_YP   4224
#define SE_B    278784

// d_ws layout (bytes)
#define WT_BYTES 1327104                  // 81*8192*2
#define XE_OFF   WT_BYTES
#define XE_BYTES (XE_B * 8 * 2)           // 35,684,352
#define SE_OFF   (XE_OFF + XE_BYTES)

typedef __attribute__((ext_vector_type(8))) __bf16 bf16x8;
typedef __attribute__((ext_vector_type(4))) float  f32x4;

// --------------------------------------------------------------------------
// Weight prep, NEW K-order. wt3[step(81)][wc(4)][n(2)][ks(2)][lane(64)][8].
// Spline step s = grp*9 + j (j = kh*3+kw): granule q = ks*4+g4 -> channel
// c = grp*8+q, elem e -> grid g: k_orig = (c*9+j)*8 + e.
// Base step bs (block 72+bs, bs = j): granule q = channel-octet, elem e ->
// channel c = q*8+e: f_orig = c*9 + j.
// --------------------------------------------------------------------------
__global__ __launch_bounds__(256)
void prep_wt(const float* __restrict__ sw, const float* __restrict__ bw,
             __bf16* __restrict__ wt3)
{
  const int bid  = blockIdx.x;
  const int t    = threadIdx.x;
  const int wc   = t >> 6;
  const int lane = t & 63;
  const int l15  = lane & 15;
  const int g4   = lane >> 4;
#pragma unroll
  for (int n = 0; n < 2; ++n)
#pragma unroll
    for (int ks = 0; ks < 2; ++ks) {
      const int co = wc * 32 + n * 16 + l15;
      const int q  = ks * 4 + g4;
      bf16x8 v;
      if (bid < NSPL_STEPS) {
        const int grp = bid / 9, j = bid - 9 * grp;
        const int c   = grp * 8 + q;
#pragma unroll
        for (int e = 0; e < 8; ++e)
          v[e] = (__bf16)sw[(size_t)((c * 9 + j) * 8 + e) * C_OUT + co];
      } else {
        const int j = bid - NSPL_STEPS;
#pragma unroll
        for (int e = 0; e < 8; ++e)
          v[e] = (__bf16)bw[(size_t)((q * 8 + e) * 9 + j) * C_OUT + co];
      }
      *(bf16x8*)(wt3 + (size_t)bid * 8192 + wc * 2048 + (n * 2 + ks) * 512
                 + lane * 8) = v;
    }
}

// --------------------------------------------------------------------------
// XE expansion: one block per (b, yp, grp); computes 66 xp x 8 cg basis
// granules into LDS, then copies the 8448B row-block out contiguously.
// --------------------------------------------------------------------------
__global__ __launch_bounds__(256)
void expand_xe(const float* __restrict__ x, const float* __restrict__ grid,
               __bf16* __restrict__ xe)
{
  __shared__ __align__(16) __bf16 buf[528 * 8];
  const int bid = blockIdx.x;           // 8*66*8 = 4224
  const int b   = bid / 528;
  const int r   = bid - b * 528;
  const int yp  = r >> 3;
  const int grp = r & 7;
  const int t   = threadIdx.x;

  float gv[NG];
#pragma unroll
  for (int g = 0; g < NG; ++g) gv[g] = grid[g];

  for (int i = t; i < 528; i += 256) {  // i = xp*8 + cg
    const int xp = i >> 3;
    const int cg = i & 7;
    const int c  = grp * 8 + cg;
    float p = 0.f;
    if (xp >= 1 && xp <= HW_DIM && yp >= 1 && yp <= HW_DIM)
      p = x[(size_t)(b * C_IN + c) * (HW_DIM * HW_DIM)
            + (yp - 1) * HW_DIM + (xp - 1)];
    bf16x8 v;
#pragma unroll
    for (int g = 0; g < NG; ++g) {
      const float z = 1.75f * (p - gv[g]);
      v[g] = (__bf16)__expf(-z * z);
    }
    *(bf16x8*)(buf + i * 8) = v;
  }
  __syncthreads();
  __bf16* dst = xe + (size_t)b * XE_B + yp * XE_YP + grp * XE_GRP;
  for (int i = t; i < 528; i += 256)
    *(bf16x8*)(dst + i * 8) = *(const bf16x8*)(buf + i * 8);
}

// --------------------------------------------------------------------------
// SE expansion: one block per (b, yp); 66 xp x 64 c silu values.
// --------------------------------------------------------------------------
__global__ __launch_bounds__(256)
void expand_se(const float* __restrict__ x, __bf16* __restrict__ se)
{
  __shared__ __align__(16) __bf16 buf[4224];
  const int bid = blockIdx.x;           // 8*66 = 528
  const int b   = bid / 66;
  const int yp  = bid - b * 66;
  const int t   = threadIdx.x;

  for (int i = t; i < 4224; i += 256) { // i = xp*64 + c
    const int xp = i >> 6;
    const int c  = i & 63;
    float p = 0.f;
    if (xp >= 1 && xp <= HW_DIM && yp >= 1 && yp <= HW_DIM)
      p = x[(size_t)(b * C_IN + c) * (HW_DIM * HW_DIM)
            + (yp - 1) * HW_DIM + (xp - 1)];
    const float e = __expf(-p);
    buf[i] = (__bf16)(p * __builtin_amdgcn_rcpf(1.f + e));
  }
  __syncthreads();
  __bf16* dst = se + (size_t)b * SE_B + yp * SE_YP;
  for (int i = t; i < 528; i += 256)
    *(bf16x8*)(dst + i * 8) = *(const bf16x8*)(buf + i * 8);
}

static __device__ __forceinline__ void gload16(const __bf16* g, __bf16* l) {
  __builtin_amdgcn_global_load_lds(
      (const __attribute__((address_space(1))) void*)g,
      (__attribute__((address_space(3))) void*)l, 16, 0, 0);
}

// counted-vmcnt barrier (T4): keep 6 newest VMEM ops in flight across it
#define WAITBAR6() do {                                      \
    asm volatile("s_waitcnt vmcnt(6)" ::: "memory");         \
    __builtin_amdgcn_s_barrier();                            \
    __builtin_amdgcn_sched_barrier(0);                       \
  } while (0)

// --------------------------------------------------------------------------
// GEMM (r8 structure, contiguous staging): 512 blocks (1 image row) x 4
// waves (64px x 32co). Spline: 72 steps, distance-2 LDS ring, 6 VMEM
// ops/thread/step (2 gload_lds + 4 b128 B-frags), vmcnt(6) barriers. Each
// staging wave now reads ONE contiguous 1KB window of XE4 (no gathers).
// Base: 9 LDS steps from SE4 (16B vector loads). Epilogue: bias + store.
// --------------------------------------------------------------------------
__global__ __launch_bounds__(256, 2)
void kan_gemm(const __bf16* __restrict__ xe, const __bf16* __restrict__ se,
              const __bf16* __restrict__ wt3, const float* __restrict__ base_b,
              float* __restrict__ out)
{
  __shared__ __align__(16) __bf16 As[3][BM][64];   // 3 x 8 KB ring

  const int t    = threadIdx.x;
  const int lane = t & 63;
  const int wid  = t >> 6;              // 0..3 = co-quarter
  const int l15  = lane & 15;
  const int g4   = lane >> 4;

  // bijective XCD swizzle: 512 blocks = 8 XCDs x 64 -> one image per XCD
  const int bid = blockIdx.x;
  const int swz = (bid & 7) * 64 + (bid >> 3);
  const int b   = swz >> 6;             // image
  const int y0  = swz & 63;             // image row

  // A-staging: slot (px = t>>3 [+32], gslot = t&7) holds feature-granule
  // q = gslot ^ (px&7); source = contiguous window + px*128B + q*16B.
  const int px0 = t >> 3;               // 0..31
  const int qs  = (t & 7) ^ (px0 & 7);  // same for px0+32 (32 = 0 mod 8)

  f32x4 acc[2][4];
#pragma unroll
  for (int n = 0; n < 2; ++n)
#pragma unroll
    for (int m = 0; m < 4; ++m)
      acc[n][m] = f32x4{0.f, 0.f, 0.f, 0.f};

  const __bf16* xeb = xe + (size_t)b * XE_B + y0 * XE_YP;

  auto stageA = [&](int buf, int s) {
    const int grp = s / 9, j = s - 9 * grp;
    const int kh = j / 3, kw = j - 3 * (j / 3);
    const __bf16* src = xeb + kh * XE_YP + grp * XE_GRP + kw * XE_XP
                      + px0 * 64 + qs * 8;
    __bf16* dst = &As[buf][0][0] + t * 8;
    gload16(src,        dst);
    gload16(src + 2048, dst + 2048);    // px += 32 (32*64 elems)
  };

  auto loadB = [&](bf16x8 (&wf)[2][2], int step) {
    const __bf16* wb = wt3 + (size_t)step * 8192 + wid * 2048 + lane * 8;
#pragma unroll
    for (int n = 0; n < 2; ++n)
#pragma unroll
      for (int ks = 0; ks < 2; ++ks)
        wf[n][ks] = *(const bf16x8*)(wb + (n * 2 + ks) * 512);
  };

  auto compute = [&](int buf, bf16x8 (&wf)[2][2]) {
    bf16x8 xf[4][2];
#pragma unroll
    for (int ks = 0; ks < 2; ++ks)
#pragma unroll
      for (int m = 0; m < 4; ++m) {
        const int pr = m * 16 + l15;
        xf[m][ks] = *(const bf16x8*)(&As[buf][pr][(((ks * 4 + g4) ^ (pr & 7)) * 8)]);
      }
#pragma unroll
    for (int ks = 0; ks < 2; ++ks)
#pragma unroll
      for (int n = 0; n < 2; ++n)
#pragma unroll
        for (int m = 0; m < 4; ++m)
          acc[n][m] = __builtin_amdgcn_mfma_f32_16x16x32_bf16(
              wf[n][ks], xf[m][ks], acc[n][m], 0, 0, 0);
  };

  // ---- spline: 72 steps, distance-2 ring, counted-vmcnt barriers ----
  bf16x8 wA[2][2], wB[2][2], wC[2][2];
  stageA(0, 0); loadB(wA, 0);           // 6 VMEM ops
  stageA(1, 1); loadB(wB, 1);           // 6 VMEM ops
  WAITBAR6();                           // step-0 landed; step-1 in flight

  for (int s = 0; s < NSPL_STEPS - 3; s += 3) {
    stageA(2, s + 2); loadB(wC, s + 2);
    compute(0, wA);
    WAITBAR6();
    stageA(0, s + 3); loadB(wA, s + 3);
    compute(1, wB);
    WAITBAR6();
    stageA(1, s + 4); loadB(wB, s + 4);
    compute(2, wC);
    WAITBAR6();
  }
  // steps 69..71 (69/buf0, 70/buf1 staged; stage 71 here)
  stageA(2, 71); loadB(wC, 71);
  compute(0, wA);                       // step 69
  WAITBAR6();                           // 70 landed; 71 in flight
  compute(1, wB);                       // step 70
  asm volatile("s_waitcnt vmcnt(0)" ::: "memory");
  __builtin_amdgcn_s_barrier();
  __builtin_amdgcn_sched_barrier(0);
  compute(2, wC);                       // step 71

  // ---- base phase: silu via LDS, 9 steps (16B vector loads from SE4) ----
  const __bf16* seb = se + (size_t)b * SE_B + y0 * SE_YP;
  auto stageBase = [&](int buf, int j) {
    const int kh = j / 3, kw = j - 3 * (j / 3);
    const int px = t & 63;
    const __bf16* src = seb + kh * SE_YP + (px + kw) * SE_XP;
#pragma unroll
    for (int h = 0; h < 2; ++h) {
      const int q = (t >> 6) + h * 4;   // channel-octet granule
      const bf16x8 v = *(const bf16x8*)(src + q * 8);
      *(bf16x8*)(&As[buf][px][((q ^ (px & 7)) * 8)]) = v;   // conflict-free
    }
  };

  stageBase(0, 0);                      // buf0 free (last compute used buf2)
  __syncthreads();
  for (int bs = 0; bs < NBASE; ++bs) {
    const int cb = bs & 1;
    if (bs + 1 < NBASE) stageBase(cb ^ 1, bs + 1);
    loadB(wA, NSPL_STEPS + bs);
    compute(cb, wA);
    __syncthreads();
  }

  // ---- epilogue: D[co][pix]; l15 -> consecutive x: coalesced ----
#pragma unroll
  for (int n = 0; n < 2; ++n) {
    const int co = wid * 32 + n * 16 + g4 * 4;
#pragma unroll
    for (int m = 0; m < 4; ++m) {
      const int pl = m * 16 + l15;
      float* o = out + (size_t)(b * C_OUT + co) * 4096 + y0 * 64 + pl;
#pragma unroll
      for (int i = 0; i < 4; ++i)
        o[(size_t)i * 4096] = acc[n][m][i] + base_b[co + i];
    }
  }
}

extern "C" void kernel_launch(void* const* d_in, const int* in_sizes, int n_in,
                              void* d_out, int out_size, void* d_ws, size_t ws_size,
                              hipStream_t stream) {
  const float* x    = (const float*)d_in[0];
  const float* grid = (const float*)d_in[1];
  const float* sw   = (const float*)d_in[2];
  const float* bw   = (const float*)d_in[3];
  const float* bb   = (const float*)d_in[4];
  float* out = (float*)d_out;

  __bf16* wt3 = (__bf16*)d_ws;
  __bf16* xe  = (__bf16*)((char*)d_ws + XE_OFF);
  __bf16* se  = (__bf16*)((char*)d_ws + SE_OFF);

  prep_wt<<<NSTEPS, 256, 0, stream>>>(sw, bw, wt3);
  expand_xe<<<4224, 256, 0, stream>>>(x, grid, xe);
  expand_se<<<528, 256, 0, stream>>>(x, se);
  kan_gemm<<<512, 256, 0, stream>>>(xe, se, wt3, bb, out);
}